// Round 19
// baseline (500.561 us; speedup 1.0000x reference)
//
#include <hip/hip_runtime.h>
#include <hip/hip_fp16.h>

#define N_HITS 30000
#define N_EDGES 90000
#define N_SPS 30000
#define HD 128
#define NCLS 5

#define PADM 136  // 128 + 8 f16 pad

typedef __attribute__((ext_vector_type(8))) _Float16 f16x8;
typedef __attribute__((ext_vector_type(4))) float floatx4;

__device__ __forceinline__ float2 h2f2(uint u) {
    union { uint u; __half2 h; } x; x.u = u;
    return __half22float2(x.h);
}
__device__ __forceinline__ uint f2h2(float a, float b) {
    union { uint u; __half2 h; } x;
    x.h = __halves2half2(__float2half(a), __float2half(b));
    return x.u;
}

// ---------------- histograms ----------------
__global__ void hist_all_kernel(const int* __restrict__ eu, const int* __restrict__ ev,
                                const int* __restrict__ ey, const int* __restrict__ nu,
                                const int* __restrict__ nv, const int* __restrict__ ny,
                                int* __restrict__ cnt) {
    int gid = blockIdx.x * blockDim.x + threadIdx.x;
    if (gid >= 450000) return;
    int p = gid / 150000;
    int r = gid - p * 150000;
    const int* e = (p == 0) ? eu : (p == 1) ? ev : ey;
    const int* nx = (p == 0) ? nu : (p == 1) ? nv : ny;
    if (r < N_EDGES) {
        atomicAdd(&cnt[p * 30000 + e[N_EDGES + r]], 1);
    } else if (r < N_EDGES + N_SPS) {
        int i = r - N_EDGES;
        atomicAdd(&cnt[(3 + p) * 30000 + nx[N_SPS + i]], 1);
    } else {
        int i = r - N_EDGES - N_SPS;
        atomicAdd(&cnt[(6 + p) * 30000 + nx[i]], 1);
    }
}

// ---------------- exclusive scan per segment ----------------
__launch_bounds__(1024)
__global__ void scan_kernel(const int* __restrict__ cnt, int* __restrict__ off,
                            int* __restrict__ cursor) {
    int seg = blockIdx.x;
    const int* c = cnt + seg * 30000;
    int* o = off + seg * 30001;
    int* cur = cursor + seg * 30000;
    int t = threadIdx.x;
    int base = t * 30;
    int lc[30];
    int sum = 0;
#pragma unroll
    for (int k = 0; k < 30; ++k) {
        int i = base + k;
        lc[k] = (i < 30000) ? c[i] : 0;
        sum += lc[k];
    }
    __shared__ int part[1024];
    part[t] = sum;
    __syncthreads();
    for (int d = 1; d < 1024; d <<= 1) {
        int x = (t >= d) ? part[t - d] : 0;
        __syncthreads();
        part[t] += x;
        __syncthreads();
    }
    int run = part[t] - sum;
#pragma unroll
    for (int k = 0; k < 30; ++k) {
        int i = base + k;
        if (i < 30000) { o[i] = run; cur[i] = run; run += lc[k]; }
    }
    if (t == 1023) o[30000] = part[1023];
}

// ---------------- CSR fill ----------------
__global__ void fill_kernel(const int* __restrict__ eu, const int* __restrict__ ev,
                            const int* __restrict__ ey, const int* __restrict__ nu,
                            const int* __restrict__ nv, const int* __restrict__ ny,
                            int* __restrict__ cursor, int* __restrict__ csr_e,
                            int* __restrict__ csr_s, int* __restrict__ csr_h) {
    int gid = blockIdx.x * blockDim.x + threadIdx.x;
    if (gid >= 450000) return;
    int p = gid / 150000;
    int r = gid - p * 150000;
    const int* e = (p == 0) ? eu : (p == 1) ? ev : ey;
    const int* nx = (p == 0) ? nu : (p == 1) ? nv : ny;
    if (r < N_EDGES) {
        int d = e[N_EDGES + r];
        int pos = atomicAdd(&cursor[p * 30000 + d], 1);
        csr_e[p * N_EDGES + pos] = e[r];
    } else if (r < N_EDGES + N_SPS) {
        int i = r - N_EDGES;
        int spid = nx[N_SPS + i];
        int pos = atomicAdd(&cursor[(3 + p) * 30000 + spid], 1);
        csr_s[p * N_SPS + pos] = nx[i];
    } else {
        int i = r - N_EDGES - N_SPS;
        int hit = nx[i];
        int pos = atomicAdd(&cursor[(6 + p) * 30000 + hit], 1);
        csr_h[p * N_SPS + pos] = nx[N_SPS + i];
    }
}

// ---------------- weight pre-pack (f16) ----------------
__device__ __forceinline__ void pack4(const float* __restrict__ W, _Float16* __restrict__ P,
                                      int idx, int koff) {
    int j = idx & 7, lane = (idx >> 3) & 63, ks = (idx >> 9) & 3, n = (idx >> 11) & 7;
    int k = ks * 32 + (lane >> 4) * 8 + j, col = n * 16 + (lane & 15);
    P[idx] = (_Float16)W[(k + koff) * 128 + col];
}
__device__ __forceinline__ void pack8(const float* __restrict__ W, _Float16* __restrict__ P, int idx) {
    int j = idx & 7, lane = (idx >> 3) & 63, ks = (idx >> 9) & 7, n = (idx >> 12) & 7;
    int k = ks * 32 + (lane >> 4) * 8 + j, col = n * 16 + (lane & 15);
    P[idx] = (_Float16)W[k * 128 + col];
}

__global__ void wprep_kernel(const float* __restrict__ W1, const float* __restrict__ W2,
                             const float* __restrict__ Wu, const float* __restrict__ Wn,
                             const float* __restrict__ Wsp, _Float16* __restrict__ packs) {
    int gid = blockIdx.x * blockDim.x + threadIdx.x;
    if (gid < 16384) { pack4(W1, packs, gid, 0); return; }            // W1d
    gid -= 16384;
    if (gid < 16384) { pack4(W1, packs + 16384, gid, 128); return; }  // W1s
    gid -= 16384;
    if (gid < 16384) { pack4(W2, packs + 32768, gid, 0); return; }    // W2
    gid -= 16384;
    if (gid < 32768) { pack8(Wu, packs + 49152, gid); return; }       // W_upd
    gid -= 32768;
    if (gid < 32768) { pack8(Wn, packs + 81920, gid); return; }       // W_nx
    gid -= 32768;
    if (gid < 16384) { pack4(Wsp, packs + 114688, gid, 0); }          // W_sp
}

// ---------------- fused encoder + y emission ----------------
__launch_bounds__(256, 4)
__global__ void enc_y_kernel(const float* __restrict__ xu, const float* __restrict__ xv,
                             const float* __restrict__ xy, const float* __restrict__ We,
                             const float* __restrict__ be, const _Float16* __restrict__ W1dP,
                             const _Float16* __restrict__ W1sP, _Float16* __restrict__ h,
                             _Float16* __restrict__ y_d, _Float16* __restrict__ y_s) {
    __shared__ _Float16 sA[128 * PADM];
    __shared__ _Float16 sO[128 * PADM];
    int t = threadIdx.x;
    int n0b = blockIdx.x * 128;
    const int M = 3 * N_HITS;
    for (int i = t; i < 2048; i += 256) {
        int row = i >> 4, c = i & 15;
        int n = n0b + row; if (n >= M) n = M - 1;
        int p = n / N_HITS;
        int nn = n - p * N_HITS;
        const float* x = (p == 0) ? xu : (p == 1) ? xv : xy;
        float4 xv4 = *(const float4*)(x + nn * 4);
        union { _Float16 o8[8]; uint4 u; } outv;
#pragma unroll
        for (int j = 0; j < 8; ++j) {
            int col = c * 8 + j;
            float acc = be[col];
            acc = fmaf(xv4.x, We[0 * HD + col], acc);
            acc = fmaf(xv4.y, We[1 * HD + col], acc);
            acc = fmaf(xv4.z, We[2 * HD + col], acc);
            acc = fmaf(xv4.w, We[3 * HD + col], acc);
            outv.o8[j] = (_Float16)fmaxf(acc, 0.f);
        }
        *(uint4*)&sA[row * PADM + c * 8] = outv.u;
        if (n0b + row < M) ((uint4*)(h + (size_t)n * HD))[c] = outv.u;
    }
    __syncthreads();

    int lane = t & 63, wave = t >> 6;
    int lcol = lane & 15, quad = lane >> 4;
    int nt0 = wave * 2;
    bool odd = (lcol & 1) != 0;

    for (int half = 0; half < 2; ++half) {
        const f16x8* wp = (const f16x8*)(half == 0 ? W1dP : W1sP);
        _Float16* out = half == 0 ? y_d : y_s;
        f16x8 B[2][4];
#pragma unroll
        for (int nt = 0; nt < 2; ++nt)
#pragma unroll
            for (int ks = 0; ks < 4; ++ks)
                B[nt][ks] = wp[((nt0 + nt) * 4 + ks) * 64 + lane];
        floatx4 acc[8][2];
#pragma unroll
        for (int mt = 0; mt < 8; ++mt) { acc[mt][0] = (floatx4){0,0,0,0}; acc[mt][1] = (floatx4){0,0,0,0}; }
#pragma unroll
        for (int mt = 0; mt < 8; ++mt)
#pragma unroll
            for (int ks = 0; ks < 4; ++ks) {
                f16x8 a = *(const f16x8*)&sA[(mt * 16 + lcol) * PADM + ks * 32 + quad * 8];
                acc[mt][0] = __builtin_amdgcn_mfma_f32_16x16x32_f16(a, B[0][ks], acc[mt][0], 0, 0, 0);
                acc[mt][1] = __builtin_amdgcn_mfma_f32_16x16x32_f16(a, B[1][ks], acc[mt][1], 0, 0, 0);
            }
#pragma unroll
        for (int mt = 0; mt < 8; ++mt)
#pragma unroll
            for (int r = 0; r < 4; ++r) {
                float v0 = acc[mt][0][r], v1 = acc[mt][1][r];
                float p0 = __shfl_xor(v0, 1), p1 = __shfl_xor(v1, 1);
                float av = odd ? p1 : v0, bv = odd ? v1 : p0;
                int col = nt0 * 16 + (odd ? 15 + lcol : lcol);
                *(uint*)&sO[(mt * 16 + quad * 4 + r) * PADM + col] = f2h2(av, bv);
            }
        __syncthreads();
        for (int i = t; i < 2048; i += 256) {
            int row = i >> 4, c = i & 15;
            int n = n0b + row;
            if (n < M) ((uint4*)(out + (size_t)n * HD))[c] = *(uint4*)&sO[row * PADM + c * 8];
        }
        __syncthreads();
    }
}

// ---------------- planar update, M=64, single LDS buffer, 4-peel gather ----------------
#define ECAP 640
__launch_bounds__(256, 5)
__global__ void update_planar_kernel(_Float16* __restrict__ h, const _Float16* __restrict__ y_d,
                                     const _Float16* __restrict__ y_s,
                                     const int* __restrict__ off, const int* __restrict__ csr_e,
                                     const float* __restrict__ b1,
                                     const _Float16* __restrict__ W2P, const float* __restrict__ b2,
                                     const _Float16* __restrict__ WuP, const float* __restrict__ bu) {
    int p = blockIdx.y;
    _Float16* hp = h + (size_t)p * N_HITS * HD;
    const _Float16* ydp = y_d + (size_t)p * N_HITS * HD;
    const _Float16* ysp = y_s + (size_t)p * N_HITS * HD;
    const int* o = off + p * 30001;
    const int* csr = csr_e + p * N_EDGES;

    __shared__ _Float16 sA[64 * PADM];
    __shared__ int sOff[65];
    __shared__ int sIdx[ECAP];
    int t = threadIdx.x;
    int n0b = blockIdx.x * 64;
    int lane = t & 63, wave = t >> 6;
    int lcol = lane & 15, quad = lane >> 4;
    int nt0 = wave * 2;
    bool odd = (lcol & 1) != 0;

    if (t < 65) {
        int idx = n0b + t; if (idx > N_HITS) idx = N_HITS;
        sOff[t] = o[idx];
    }
    for (int i = t; i < 1024; i += 256) {
        int row = i >> 4, c = i & 15;
        int n = n0b + row; if (n >= N_HITS) n = N_HITS - 1;
        f16x8 yv = *(const f16x8*)&ydp[(size_t)n * HD + c * 8];
        float4 b1a = *(const float4*)(b1 + c * 8);
        float4 b1b = *(const float4*)(b1 + c * 8 + 4);
        float bb[8] = {b1a.x, b1a.y, b1a.z, b1a.w, b1b.x, b1b.y, b1b.z, b1b.w};
        f16x8 ov;
#pragma unroll
        for (int j = 0; j < 8; ++j) ov[j] = (_Float16)((float)yv[j] + bb[j]);
        *(f16x8*)&sA[row * PADM + c * 8] = ov;
    }
    __syncthreads();
    int base = sOff[0];
    int total = sOff[64] - base;
    bool useL = (total <= ECAP);
    if (useL) for (int i = t; i < total; i += 256) sIdx[i] = csr[base + i];
    __syncthreads();

    // phase A: in-place CSR edge gather, 4-peel + 2-way loop
    for (int i = t; i < 1024; i += 256) {
        int row = i >> 4, c = i & 15;
        int d = n0b + row;
        int beg = 0, end = 0;
        if (d < N_HITS) { beg = sOff[row]; end = sOff[row + 1]; }
        f16x8 ydv = *(const f16x8*)&sA[row * PADM + c * 8];
        f16x8 a0 = (f16x8)(_Float16)0, a1 = (f16x8)(_Float16)0;
        f16x8 a2 = (f16x8)(_Float16)0, a3 = (f16x8)(_Float16)0;
        int k = beg;
        int rem = end - beg;
        if (rem > 0) {
            int s0 = useL ? sIdx[k - base] : csr[k];
            int s1 = (rem > 1) ? (useL ? sIdx[k + 1 - base] : csr[k + 1]) : s0;
            int s2 = (rem > 2) ? (useL ? sIdx[k + 2 - base] : csr[k + 2]) : s0;
            int s3 = (rem > 3) ? (useL ? sIdx[k + 3 - base] : csr[k + 3]) : s0;
            f16x8 v0 = *(const f16x8*)&ysp[(size_t)s0 * HD + c * 8];
            f16x8 v1 = *(const f16x8*)&ysp[(size_t)s1 * HD + c * 8];
            f16x8 v2 = *(const f16x8*)&ysp[(size_t)s2 * HD + c * 8];
            f16x8 v3 = *(const f16x8*)&ysp[(size_t)s3 * HD + c * 8];
            a0 += __builtin_elementwise_max(v0 + ydv, (f16x8)(_Float16)0);
            if (rem > 1) a1 += __builtin_elementwise_max(v1 + ydv, (f16x8)(_Float16)0);
            if (rem > 2) a2 += __builtin_elementwise_max(v2 + ydv, (f16x8)(_Float16)0);
            if (rem > 3) a3 += __builtin_elementwise_max(v3 + ydv, (f16x8)(_Float16)0);
            k += (rem < 4) ? rem : 4;
        }
        for (; k + 2 <= end; k += 2) {
            int s0 = useL ? sIdx[k - base] : csr[k];
            int s1 = useL ? sIdx[k + 1 - base] : csr[k + 1];
            f16x8 v0 = *(const f16x8*)&ysp[(size_t)s0 * HD + c * 8];
            f16x8 v1 = *(const f16x8*)&ysp[(size_t)s1 * HD + c * 8];
            a0 += __builtin_elementwise_max(v0 + ydv, (f16x8)(_Float16)0);
            a1 += __builtin_elementwise_max(v1 + ydv, (f16x8)(_Float16)0);
        }
        if (k < end) {
            int s0 = useL ? sIdx[k - base] : csr[k];
            f16x8 v0 = *(const f16x8*)&ysp[(size_t)s0 * HD + c * 8];
            a0 += __builtin_elementwise_max(v0 + ydv, (f16x8)(_Float16)0);
        }
        f16x8 accv = (a0 + a1) + (a2 + a3);
        _Float16 iv = (_Float16)((end > beg) ? 1.f / (float)(end - beg) : 0.f);
        accv *= iv;
        *(f16x8*)&sA[row * PADM + c * 8] = accv;
    }
    __syncthreads();
    // phase B: agg = z @ W2 + b2
    floatx4 acc[4][2];
    {
        const f16x8* w2p = (const f16x8*)W2P;
        f16x8 B[2][4];
#pragma unroll
        for (int nt = 0; nt < 2; ++nt)
#pragma unroll
            for (int ks = 0; ks < 4; ++ks)
                B[nt][ks] = w2p[((nt0 + nt) * 4 + ks) * 64 + lane];
#pragma unroll
        for (int nt = 0; nt < 2; ++nt) {
            float bv = b2[(nt0 + nt) * 16 + lcol];
#pragma unroll
            for (int mt = 0; mt < 4; ++mt) acc[mt][nt] = (floatx4){bv, bv, bv, bv};
        }
#pragma unroll
        for (int mt = 0; mt < 4; ++mt)
#pragma unroll
            for (int ks = 0; ks < 4; ++ks) {
                f16x8 a = *(const f16x8*)&sA[(mt * 16 + lcol) * PADM + ks * 32 + quad * 8];
                acc[mt][0] = __builtin_amdgcn_mfma_f32_16x16x32_f16(a, B[0][ks], acc[mt][0], 0, 0, 0);
                acc[mt][1] = __builtin_amdgcn_mfma_f32_16x16x32_f16(a, B[1][ks], acc[mt][1], 0, 0, 0);
            }
    }
    __syncthreads();
    // phase C: agg -> sA
#pragma unroll
    for (int mt = 0; mt < 4; ++mt)
#pragma unroll
        for (int r = 0; r < 4; ++r) {
            float v0 = acc[mt][0][r], v1 = acc[mt][1][r];
            float p0 = __shfl_xor(v0, 1), p1 = __shfl_xor(v1, 1);
            float av = odd ? p1 : v0, bv = odd ? v1 : p0;
            int col = nt0 * 16 + (odd ? 15 + lcol : lcol);
            *(uint*)&sA[(mt * 16 + quad * 4 + r) * PADM + col] = f2h2(av, bv);
        }
    __syncthreads();
    // phase D: accU = bu + agg @ Wu[ks4..7]
    {
        const f16x8* wu = (const f16x8*)WuP;
        f16x8 B[2][4];
#pragma unroll
        for (int nt = 0; nt < 2; ++nt)
#pragma unroll
            for (int ks = 0; ks < 4; ++ks)
                B[nt][ks] = wu[((nt0 + nt) * 8 + 4 + ks) * 64 + lane];
        floatx4 tmp[4][2];
#pragma unroll
        for (int nt = 0; nt < 2; ++nt) {
            float bv = bu[(nt0 + nt) * 16 + lcol];
#pragma unroll
            for (int mt = 0; mt < 4; ++mt) tmp[mt][nt] = (floatx4){bv, bv, bv, bv};
        }
#pragma unroll
        for (int mt = 0; mt < 4; ++mt)
#pragma unroll
            for (int ks = 0; ks < 4; ++ks) {
                f16x8 a = *(const f16x8*)&sA[(mt * 16 + lcol) * PADM + ks * 32 + quad * 8];
                tmp[mt][0] = __builtin_amdgcn_mfma_f32_16x16x32_f16(a, B[0][ks], tmp[mt][0], 0, 0, 0);
                tmp[mt][1] = __builtin_amdgcn_mfma_f32_16x16x32_f16(a, B[1][ks], tmp[mt][1], 0, 0, 0);
            }
#pragma unroll
        for (int mt = 0; mt < 4; ++mt) { acc[mt][0] = tmp[mt][0]; acc[mt][1] = tmp[mt][1]; }
    }
    __syncthreads();
    // phase E: stage h -> sA
    for (int i = t; i < 1024; i += 256) {
        int row = i >> 4, c = i & 15;
        int n = n0b + row; if (n >= N_HITS) n = N_HITS - 1;
        *(uint4*)&sA[row * PADM + c * 8] = ((const uint4*)(hp + (size_t)n * HD))[c];
    }
    __syncthreads();
    // phase F: accU += h @ Wu[ks0..3]
    {
        const f16x8* wu = (const f16x8*)WuP;
        f16x8 B[2][4];
#pragma unroll
        for (int nt = 0; nt < 2; ++nt)
#pragma unroll
            for (int ks = 0; ks < 4; ++ks)
                B[nt][ks] = wu[((nt0 + nt) * 8 + ks) * 64 + lane];
#pragma unroll
        for (int mt = 0; mt < 4; ++mt)
#pragma unroll
            for (int ks = 0; ks < 4; ++ks) {
                f16x8 a = *(const f16x8*)&sA[(mt * 16 + lcol) * PADM + ks * 32 + quad * 8];
                acc[mt][0] = __builtin_amdgcn_mfma_f32_16x16x32_f16(a, B[0][ks], acc[mt][0], 0, 0, 0);
                acc[mt][1] = __builtin_amdgcn_mfma_f32_16x16x32_f16(a, B[1][ks], acc[mt][1], 0, 0, 0);
            }
    }
    __syncthreads();
    // phase G: h_new = h(sA) + relu(accU) -> sA
#pragma unroll
    for (int mt = 0; mt < 4; ++mt)
#pragma unroll
        for (int r = 0; r < 4; ++r) {
            float v0 = fmaxf(acc[mt][0][r], 0.f), v1 = fmaxf(acc[mt][1][r], 0.f);
            float p0 = __shfl_xor(v0, 1), p1 = __shfl_xor(v1, 1);
            float av = odd ? p1 : v0, bv = odd ? v1 : p0;
            int col = nt0 * 16 + (odd ? 15 + lcol : lcol);
            uint* sp2 = (uint*)&sA[(mt * 16 + quad * 4 + r) * PADM + col];
            float2 ho = h2f2(*sp2);
            *sp2 = f2h2(ho.x + av, ho.y + bv);
        }
    __syncthreads();
    // phase H: coalesced store sA -> h
    for (int i = t; i < 1024; i += 256) {
        int row = i >> 4, c = i & 15;
        int n = n0b + row;
        if (n < N_HITS) ((uint4*)(hp + (size_t)n * HD))[c] = *(uint4*)&sA[row * PADM + c * 8];
    }
}

// ---------------- sp fused (M=64) ----------------
#define SCAP 576
__launch_bounds__(256, 6)
__global__ void sp_fused_kernel(const _Float16* __restrict__ h, const int* __restrict__ off,
                                const int* __restrict__ csr_s, const _Float16* __restrict__ WspP,
                                const float* __restrict__ b, _Float16* __restrict__ spf) {
    __shared__ _Float16 sA[64 * PADM];
    __shared__ int sOff[3][65];
    __shared__ int sIdx[SCAP];
    int t = threadIdx.x;
    int n0b = blockIdx.x * 64;
    int lane = t & 63, wave = t >> 6;
    int lcol = lane & 15, quad = lane >> 4;
    int nt0 = wave * 2;
    bool odd = (lcol & 1) != 0;

    if (t < 195) {
        int p = t / 65, i = t - p * 65;
        int idx = n0b + i; if (idx > N_SPS) idx = N_SPS;
        sOff[p][i] = off[(3 + p) * 30001 + idx];
    }
    __syncthreads();
    int base0 = sOff[0][0], len0 = sOff[0][64] - base0;
    int base1 = sOff[1][0], len1 = sOff[1][64] - base1;
    int base2 = sOff[2][0], len2 = sOff[2][64] - base2;
    int ofs1 = len0, ofs2 = len0 + len1;
    bool useL = (ofs2 + len2 <= SCAP);
    if (useL) {
        for (int i = t; i < len0; i += 256) sIdx[i] = csr_s[base0 + i];
        for (int i = t; i < len1; i += 256) sIdx[ofs1 + i] = csr_s[N_SPS + base1 + i];
        for (int i = t; i < len2; i += 256) sIdx[ofs2 + i] = csr_s[2 * N_SPS + base2 + i];
    }
    __syncthreads();

    for (int i = t; i < 1024; i += 256) {
        int row = i >> 4, c = i & 15;
        int s = n0b + row;
        f16x8 tv = (f16x8)(_Float16)0;
        if (s < N_SPS) {
#pragma unroll
            for (int p = 0; p < 3; ++p) {
                int beg = sOff[p][row], end = sOff[p][row + 1];
                int bb = (p == 0) ? base0 : (p == 1) ? base1 : base2;
                int oo = (p == 0) ? 0 : (p == 1) ? ofs1 : ofs2;
                const int* csr = csr_s + p * N_SPS;
                const _Float16* hb = h + (size_t)p * N_HITS * HD;
                f16x8 s0v = (f16x8)(_Float16)0, s1v = (f16x8)(_Float16)0;
                int k = beg;
                int rem = end - beg;
                if (rem > 0) {
                    int h0 = useL ? sIdx[oo + (k - bb)] : csr[k];
                    int h1 = (rem > 1) ? (useL ? sIdx[oo + (k + 1 - bb)] : csr[k + 1]) : h0;
                    f16x8 v0 = *(const f16x8*)&hb[(size_t)h0 * HD + c * 8];
                    f16x8 v1 = *(const f16x8*)&hb[(size_t)h1 * HD + c * 8];
                    s0v += v0;
                    if (rem > 1) s1v += v1;
                    k += (rem < 2) ? rem : 2;
                }
                for (; k + 2 <= end; k += 2) {
                    int h0 = useL ? sIdx[oo + (k - bb)] : csr[k];
                    int h1 = useL ? sIdx[oo + (k + 1 - bb)] : csr[k + 1];
                    f16x8 v0 = *(const f16x8*)&hb[(size_t)h0 * HD + c * 8];
                    f16x8 v1 = *(const f16x8*)&hb[(size_t)h1 * HD + c * 8];
                    s0v += v0; s1v += v1;
                }
                if (k < end) {
                    int h0 = useL ? sIdx[oo + (k - bb)] : csr[k];
                    s0v += *(const f16x8*)&hb[(size_t)h0 * HD + c * 8];
                }
                f16x8 sv = s0v + s1v;
                _Float16 iv = (_Float16)((end > beg) ? 1.f / (float)(end - beg) : 0.f);
                tv += sv * iv;
            }
        }
        *(f16x8*)&sA[row * PADM + c * 8] = tv;
    }
    __syncthreads();

    const f16x8* wp = (const f16x8*)WspP;
    f16x8 B[2][4];
#pragma unroll
    for (int nt = 0; nt < 2; ++nt)
#pragma unroll
        for (int ks = 0; ks < 4; ++ks)
            B[nt][ks] = wp[((nt0 + nt) * 4 + ks) * 64 + lane];

    floatx4 acc[4][2];
#pragma unroll
    for (int nt = 0; nt < 2; ++nt) {
        float bv = b[(nt0 + nt) * 16 + lcol];
#pragma unroll
        for (int mt = 0; mt < 4; ++mt) acc[mt][nt] = (floatx4){bv, bv, bv, bv};
    }
#pragma unroll
    for (int mt = 0; mt < 4; ++mt)
#pragma unroll
        for (int ks = 0; ks < 4; ++ks) {
            f16x8 a = *(const f16x8*)&sA[(mt * 16 + lcol) * PADM + ks * 32 + quad * 8];
            acc[mt][0] = __builtin_amdgcn_mfma_f32_16x16x32_f16(a, B[0][ks], acc[mt][0], 0, 0, 0);
            acc[mt][1] = __builtin_amdgcn_mfma_f32_16x16x32_f16(a, B[1][ks], acc[mt][1], 0, 0, 0);
        }
    __syncthreads();
#pragma unroll
    for (int mt = 0; mt < 4; ++mt)
#pragma unroll
        for (int r = 0; r < 4; ++r) {
            float v0 = fmaxf(acc[mt][0][r], 0.f), v1 = fmaxf(acc[mt][1][r], 0.f);
            float p0 = __shfl_xor(v0, 1), p1 = __shfl_xor(v1, 1);
            float av = odd ? p1 : v0, bv = odd ? v1 : p0;
            int col = nt0 * 16 + (odd ? 15 + lcol : lcol);
            *(uint*)&sA[(mt * 16 + quad * 4 + r) * PADM + col] = f2h2(av, bv);
        }
    __syncthreads();
    for (int i = t; i < 1024; i += 256) {
        int row = i >> 4, c = i & 15;
        int n = n0b + row;
        if (n < N_SPS) ((uint4*)(spf + (size_t)n * HD))[c] = *(uint4*)&sA[row * PADM + c * 8];
    }
}

// ---------------- nexus update (M=64); merged y GEMMs; last iter fuses decoder ----------------
#define HCAP 320
__launch_bounds__(256, 4)
__global__ void update_y_kernel(_Float16* __restrict__ h, const _Float16* __restrict__ sp,
                                const int* __restrict__ off, const int* __restrict__ csr_h,
                                const _Float16* __restrict__ WP, const float* __restrict__ b,
                                const _Float16* __restrict__ W1dP, const _Float16* __restrict__ W1sP,
                                _Float16* __restrict__ y_d, _Float16* __restrict__ y_s,
                                const float* __restrict__ Wsem, const float* __restrict__ bsem,
                                float* __restrict__ out, int last) {
    int p = blockIdx.y;
    _Float16* hp = h + (size_t)p * N_HITS * HD;
    _Float16* ydp = y_d + (size_t)p * N_HITS * HD;
    _Float16* ysp = y_s + (size_t)p * N_HITS * HD;
    const int* o = off + (6 + p) * 30001;
    const int* csr = csr_h + p * N_SPS;

    __shared__ _Float16 sH[64 * PADM];
    __shared__ _Float16 sA[64 * PADM];
    __shared__ int sOff[65];
    __shared__ int sIdx[HCAP];
    int t = threadIdx.x;
    int n0b = blockIdx.x * 64;
    int lane = t & 63, wave = t >> 6;
    int lcol = lane & 15, quad = lane >> 4;
    int nt0 = wave * 2;
    bool odd = (lcol & 1) != 0;

    if (t < 65) {
        int idx = n0b + t; if (idx > N_HITS) idx = N_HITS;
        sOff[t] = o[idx];
    }
    for (int i = t; i < 1024; i += 256) {
        int row = i >> 4, c = i & 15;
        int n = n0b + row; if (n >= N_HITS) n = N_HITS - 1;
        *(uint4*)&sH[row * PADM + c * 8] = ((const uint4*)(hp + (size_t)n * HD))[c];
    }
    __syncthreads();
    int base = sOff[0];
    int total = sOff[64] - base;
    bool useL = (total <= HCAP);
    if (useL) for (int i = t; i < total; i += 256) sIdx[i] = csr[base + i];
    __syncthreads();

    // phase A: gather aux -> sA (2-peel + 2-way)
    for (int i = t; i < 1024; i += 256) {
        int row = i >> 4, c = i & 15;
        int hit = n0b + row;
        int beg = 0, end = 0;
        if (hit < N_HITS) { beg = sOff[row]; end = sOff[row + 1]; }
        f16x8 a0 = (f16x8)(_Float16)0, a1 = (f16x8)(_Float16)0;
        int k = beg;
        int rem = end - beg;
        if (rem > 0) {
            int s0 = useL ? sIdx[k - base] : csr[k];
            int s1 = (rem > 1) ? (useL ? sIdx[k + 1 - base] : csr[k + 1]) : s0;
            f16x8 v0 = *(const f16x8*)&sp[(size_t)s0 * HD + c * 8];
            f16x8 v1 = *(const f16x8*)&sp[(size_t)s1 * HD + c * 8];
            a0 += v0;
            if (rem > 1) a1 += v1;
            k += (rem < 2) ? rem : 2;
        }
        for (; k + 2 <= end; k += 2) {
            int s0 = useL ? sIdx[k - base] : csr[k];
            int s1 = useL ? sIdx[k + 1 - base] : csr[k + 1];
            f16x8 v0 = *(const f16x8*)&sp[(size_t)s0 * HD + c * 8];
            f16x8 v1 = *(const f16x8*)&sp[(size_t)s1 * HD + c * 8];
            a0 += v0; a1 += v1;
        }
        if (k < end) {
            int s0 = useL ? sIdx[k - base] : csr[k];
            a0 += *(const f16x8*)&sp[(size_t)s0 * HD + c * 8];
        }
        f16x8 av8 = a0 + a1;
        _Float16 iv = (_Float16)((end > beg) ? 1.f / (float)(end - beg) : 0.f);
        av8 *= iv;
        *(f16x8*)&sA[row * PADM + c * 8] = av8;
    }
    __syncthreads();
    // phase B: acc = b + sH@Wn[ks0..3] + sA@Wn[ks4..7]
    floatx4 acc[4][2];
    {
        const f16x8* wp = (const f16x8*)WP;
        f16x8 BH[2][4], BA[2][4];
#pragma unroll
        for (int nt = 0; nt < 2; ++nt)
#pragma unroll
            for (int ks = 0; ks < 4; ++ks) {
                BH[nt][ks] = wp[((nt0 + nt) * 8 + ks) * 64 + lane];
                BA[nt][ks] = wp[((nt0 + nt) * 8 + 4 + ks) * 64 + lane];
            }
#pragma unroll
        for (int nt = 0; nt < 2; ++nt) {
            float bv = b[(nt0 + nt) * 16 + lcol];
#pragma unroll
            for (int mt = 0; mt < 4; ++mt) acc[mt][nt] = (floatx4){bv, bv, bv, bv};
        }
#pragma unroll
        for (int mt = 0; mt < 4; ++mt)
#pragma unroll
            for (int ks = 0; ks < 4; ++ks) {
                f16x8 ah = *(const f16x8*)&sH[(mt * 16 + lcol) * PADM + ks * 32 + quad * 8];
                f16x8 aa = *(const f16x8*)&sA[(mt * 16 + lcol) * PADM + ks * 32 + quad * 8];
                acc[mt][0] = __builtin_amdgcn_mfma_f32_16x16x32_f16(ah, BH[0][ks], acc[mt][0], 0, 0, 0);
                acc[mt][1] = __builtin_amdgcn_mfma_f32_16x16x32_f16(ah, BH[1][ks], acc[mt][1], 0, 0, 0);
                acc[mt][0] = __builtin_amdgcn_mfma_f32_16x16x32_f16(aa, BA[0][ks], acc[mt][0], 0, 0, 0);
                acc[mt][1] = __builtin_amdgcn_mfma_f32_16x16x32_f16(aa, BA[1][ks], acc[mt][1], 0, 0, 0);
            }
    }
    __syncthreads();
    // phase C: h_new = sH + relu(acc) -> sH
#pragma unroll
    for (int mt = 0; mt < 4; ++mt)
#pragma unroll
        for (int r = 0; r < 4; ++r) {
            float v0 = fmaxf(acc[mt][0][r], 0.f), v1 = fmaxf(acc[mt][1][r], 0.f);
            float p0 = __shfl_xor(v0, 1), p1 = __shfl_xor(v1, 1);
            float av = odd ? p1 : v0, bv = odd ? v1 : p0;
            int col = nt0 * 16 + (odd ? 15 + lcol : lcol);
            uint* sp2 = (uint*)&sH[(mt * 16 + quad * 4 + r) * PADM + col];
            float2 ho = h2f2(*sp2);
            *sp2 = f2h2(ho.x + av, ho.y + bv);
        }
    __syncthreads();
    // phase D: coalesced h store
    for (int i = t; i < 1024; i += 256) {
        int row = i >> 4, c = i & 15;
        int n = n0b + row;
        if (n < N_HITS) ((uint4*)(hp + (size_t)n * HD))[c] = *(uint4*)&sH[row * PADM + c * 8];
    }
    if (last) {
        // fused decoder: out[n] = h_new @ Wsem + bsem; 4 threads/row, 32 cols each
        int row = t >> 2, part = t & 3;
        int n = n0b + row;
        float a0 = 0.f, a1 = 0.f, a2 = 0.f, a3 = 0.f, a4 = 0.f;
        const _Float16* hr = &sH[row * PADM + part * 32];
#pragma unroll
        for (int q = 0; q < 4; ++q) {
            f16x8 v = *(const f16x8*)(hr + q * 8);
#pragma unroll
            for (int j = 0; j < 8; ++j) {
                float x = (float)v[j];
                const float* w = Wsem + (part * 32 + q * 8 + j) * NCLS;
                a0 = fmaf(x, w[0], a0);
                a1 = fmaf(x, w[1], a1);
                a2 = fmaf(x, w[2], a2);
                a3 = fmaf(x, w[3], a3);
                a4 = fmaf(x, w[4], a4);
            }
        }
        a0 += __shfl_xor(a0, 1); a0 += __shfl_xor(a0, 2);
        a1 += __shfl_xor(a1, 1); a1 += __shfl_xor(a1, 2);
        a2 += __shfl_xor(a2, 1); a2 += __shfl_xor(a2, 2);
        a3 += __shfl_xor(a3, 1); a3 += __shfl_xor(a3, 2);
        a4 += __shfl_xor(a4, 1); a4 += __shfl_xor(a4, 2);
        if (part == 0 && n < N_HITS) {
            float* oo = out + ((size_t)p * N_HITS + n) * NCLS;
            oo[0] = a0 + bsem[0]; oo[1] = a1 + bsem[1]; oo[2] = a2 + bsem[2];
            oo[3] = a3 + bsem[3]; oo[4] = a4 + bsem[4];
        }
        return;
    }
    // phase E: BOTH y GEMMs from sH back-to-back (single MFMA stream)
    floatx4 ysa[4][2], yda[4][2];
    {
        const f16x8* wys = (const f16x8*)W1sP;
        f16x8 B[2][4];
#pragma unroll
        for (int nt = 0; nt < 2; ++nt)
#pragma unroll
            for (int ks = 0; ks < 4; ++ks)
                B[nt][ks] = wys[((nt0 + nt) * 4 + ks) * 64 + lane];
#pragma unroll
        for (int mt = 0; mt < 4; ++mt) { ysa[mt][0] = (floatx4){0,0,0,0}; ysa[mt][1] = (floatx4){0,0,0,0}; }
#pragma unroll
        for (int mt = 0; mt < 4; ++mt)
#pragma unroll
            for (int ks = 0; ks < 4; ++ks) {
                f16x8 a = *(const f16x8*)&sH[(mt * 16 + lcol) * PADM + ks * 32 + quad * 8];
                ysa[mt][0] = __builtin_amdgcn_mfma_f32_16x16x32_f16(a, B[0][ks], ysa[mt][0], 0, 0, 0);
                ysa[mt][1] = __builtin_amdgcn_mfma_f32_16x16x32_f16(a, B[1][ks], ysa[mt][1], 0, 0, 0);
            }
    }
    {
        const f16x8* wyd = (const f16x8*)W1dP;
        f16x8 B[2][4];
#pragma unroll
        for (int nt = 0; nt < 2; ++nt)
#pragma unroll
            for (int ks = 0; ks < 4; ++ks)
                B[nt][ks] = wyd[((nt0 + nt) * 4 + ks) * 64 + lane];
#pragma unroll
        for (int mt = 0; mt < 4; ++mt) { yda[mt][0] = (floatx4){0,0,0,0}; yda[mt][1] = (floatx4){0,0,0,0}; }
#pragma unroll
        for (int mt = 0; mt < 4; ++mt)
#pragma unroll
            for (int ks = 0; ks < 4; ++ks) {
                f16x8 a = *(const f16x8*)&sH[(mt * 16 + lcol) * PADM + ks * 32 + quad * 8];
                yda[mt][0] = __builtin_amdgcn_mfma_f32_16x16x32_f16(a, B[0][ks], yda[mt][0], 0, 0, 0);
                yda[mt][1] = __builtin_amdgcn_mfma_f32_16x16x32_f16(a, B[1][ks], yda[mt][1], 0, 0, 0);
            }
    }
    __syncthreads();  // all sH reads (GEMMs + h store) done; sA gather reads done
    // phase F: y_s tile -> sA ; y_d tile -> sH
#pragma unroll
    for (int mt = 0; mt < 4; ++mt)
#pragma unroll
        for (int r = 0; r < 4; ++r) {
            int rowo = (mt * 16 + quad * 4 + r) * PADM;
            int col = nt0 * 16 + (odd ? 15 + lcol : lcol);
            {
                float v0 = ysa[mt][0][r], v1 = ysa[mt][1][r];
                float p0 = __shfl_xor(v0, 1), p1 = __shfl_xor(v1, 1);
                float av = odd ? p1 : v0, bv = odd ? v1 : p0;
                *(uint*)&sA[rowo + col] = f2h2(av, bv);
            }
            {
                float v0 = yda[mt][0][r], v1 = yda[mt][1][r];
                float p0 = __shfl_xor(v0, 1), p1 = __shfl_xor(v1, 1);
                float av = odd ? p1 : v0, bv = odd ? v1 : p0;
                *(uint*)&sH[rowo + col] = f2h2(av, bv);
            }
        }
    __syncthreads();
    // phase G: coalesced stores
    for (int i = t; i < 1024; i += 256) {
        int row = i >> 4, c = i & 15;
        int n = n0b + row;
        if (n < N_HITS) {
            ((uint4*)(ysp + (size_t)n * HD))[c] = *(uint4*)&sA[row * PADM + c * 8];
            ((uint4*)(ydp + (size_t)n * HD))[c] = *(uint4*)&sH[row * PADM + c * 8];
        }
    }
}

extern "C" void kernel_launch(void* const* d_in, const int* in_sizes, int n_in,
                              void* d_out, int out_size, void* d_ws, size_t ws_size,
                              hipStream_t stream) {
    const float* xu = (const float*)d_in[0];
    const int* eu = (const int*)d_in[1];
    const int* nu = (const int*)d_in[2];
    const float* xv = (const float*)d_in[3];
    const int* ev = (const int*)d_in[4];
    const int* nv = (const int*)d_in[5];
    const float* xy = (const float*)d_in[6];
    const int* ey = (const int*)d_in[7];
    const int* ny = (const int*)d_in[8];
    const float* W_enc = (const float*)d_in[9];
    const float* b_enc = (const float*)d_in[10];
    const float* W1 = (const float*)d_in[11];
    const float* b1 = (const float*)d_in[12];
    const float* W2 = (const float*)d_in[13];
    const float* b2 = (const float*)d_in[14];
    const float* W_upd = (const float*)d_in[15];
    const float* b_upd = (const float*)d_in[16];
    const float* W_sp = (const float*)d_in[17];
    const float* b_sp = (const float*)d_in[18];
    const float* W_nx = (const float*)d_in[19];
    const float* b_nx = (const float*)d_in[20];
    const float* W_sem = (const float*)d_in[21];
    const float* b_sem = (const float*)d_in[22];

    const size_t HN = (size_t)3 * N_HITS * HD;
    _Float16* h = (_Float16*)d_ws;                 // f16 [3][N_HITS][HD]
    _Float16* y_s = h + HN;                        // f16 [3][N_HITS][HD]
    _Float16* y_d = y_s + HN;                      // f16 [3][N_HITS][HD]
    _Float16* sp = y_d + HN;                       // f16 [N_SPS][HD]
    int* cnt = (int*)(sp + (size_t)N_SPS * HD);    // [270000]
    int* off = cnt + 270000;                       // [9*30001]
    int* cursor = off + 270009;                    // [270000]
    int* csr_e = cursor + 270000;                  // [3*90000]
    int* csr_s = csr_e + 270000;                   // [3*30000]
    int* csr_h = csr_s + 90000;                    // [3*30000]
    _Float16* packs = (_Float16*)(csr_h + 90000);  // [131072]
    _Float16* W1dP = packs;
    _Float16* W1sP = packs + 16384;
    _Float16* W2P = packs + 32768;
    _Float16* WuP = packs + 49152;
    _Float16* WnP = packs + 81920;
    _Float16* WspP = packs + 114688;

    wprep_kernel<<<512, 256, 0, stream>>>(W1, W2, W_upd, W_nx, W_sp, packs);
    (void)hipMemsetAsync(cnt, 0, 270000 * sizeof(int), stream);
    hist_all_kernel<<<(450000 + 255) / 256, 256, 0, stream>>>(eu, ev, ey, nu, nv, ny, cnt);
    scan_kernel<<<9, 1024, 0, stream>>>(cnt, off, cursor);
    fill_kernel<<<(450000 + 255) / 256, 256, 0, stream>>>(eu, ev, ey, nu, nv, ny,
                                                          cursor, csr_e, csr_s, csr_h);

    enc_y_kernel<<<(3 * N_HITS + 127) / 128, 256, 0, stream>>>(xu, xv, xy, W_enc, b_enc,
                                                               W1dP, W1sP, h, y_d, y_s);

    for (int it = 0; it < 3; ++it) {
        update_planar_kernel<<<dim3((N_HITS + 63) / 64, 3), 256, 0, stream>>>(
            h, y_d, y_s, off, csr_e, b1, W2P, b2, WuP, b_upd);
        sp_fused_kernel<<<(N_SPS + 63) / 64, 256, 0, stream>>>(h, off, csr_s, WspP, b_sp, sp);
        update_y_kernel<<<dim3((N_HITS + 63) / 64, 3), 256, 0, stream>>>(
            h, sp, off, csr_h, WnP, b_nx, W1dP, W1sP, y_d, y_s,
            W_sem, b_sem, (float*)d_out, it == 2 ? 1 : 0);
    }
}

// Round 20
// 492.354 us; speedup vs baseline: 1.0167x; 1.0167x over previous
//
#include <hip/hip_runtime.h>
#include <hip/hip_fp16.h>

#define N_HITS 30000
#define N_EDGES 90000
#define N_SPS 30000
#define HD 128
#define NCLS 5

#define PADM 136  // 128 + 8 f16 pad

typedef __attribute__((ext_vector_type(8))) _Float16 f16x8;
typedef __attribute__((ext_vector_type(4))) float floatx4;

__device__ __forceinline__ float2 h2f2(uint u) {
    union { uint u; __half2 h; } x; x.u = u;
    return __half22float2(x.h);
}
__device__ __forceinline__ uint f2h2(float a, float b) {
    union { uint u; __half2 h; } x;
    x.h = __halves2half2(__float2half(a), __float2half(b));
    return x.u;
}

// ---------------- histograms ----------------
__global__ void hist_all_kernel(const int* __restrict__ eu, const int* __restrict__ ev,
                                const int* __restrict__ ey, const int* __restrict__ nu,
                                const int* __restrict__ nv, const int* __restrict__ ny,
                                int* __restrict__ cnt) {
    int gid = blockIdx.x * blockDim.x + threadIdx.x;
    if (gid >= 450000) return;
    int p = gid / 150000;
    int r = gid - p * 150000;
    const int* e = (p == 0) ? eu : (p == 1) ? ev : ey;
    const int* nx = (p == 0) ? nu : (p == 1) ? nv : ny;
    if (r < N_EDGES) {
        atomicAdd(&cnt[p * 30000 + e[N_EDGES + r]], 1);
    } else if (r < N_EDGES + N_SPS) {
        int i = r - N_EDGES;
        atomicAdd(&cnt[(3 + p) * 30000 + nx[N_SPS + i]], 1);
    } else {
        int i = r - N_EDGES - N_SPS;
        atomicAdd(&cnt[(6 + p) * 30000 + nx[i]], 1);
    }
}

// ---------------- exclusive scan per segment ----------------
__launch_bounds__(1024)
__global__ void scan_kernel(const int* __restrict__ cnt, int* __restrict__ off,
                            int* __restrict__ cursor) {
    int seg = blockIdx.x;
    const int* c = cnt + seg * 30000;
    int* o = off + seg * 30001;
    int* cur = cursor + seg * 30000;
    int t = threadIdx.x;
    int base = t * 30;
    int lc[30];
    int sum = 0;
#pragma unroll
    for (int k = 0; k < 30; ++k) {
        int i = base + k;
        lc[k] = (i < 30000) ? c[i] : 0;
        sum += lc[k];
    }
    __shared__ int part[1024];
    part[t] = sum;
    __syncthreads();
    for (int d = 1; d < 1024; d <<= 1) {
        int x = (t >= d) ? part[t - d] : 0;
        __syncthreads();
        part[t] += x;
        __syncthreads();
    }
    int run = part[t] - sum;
#pragma unroll
    for (int k = 0; k < 30; ++k) {
        int i = base + k;
        if (i < 30000) { o[i] = run; cur[i] = run; run += lc[k]; }
    }
    if (t == 1023) o[30000] = part[1023];
}

// ---------------- CSR fill ----------------
__global__ void fill_kernel(const int* __restrict__ eu, const int* __restrict__ ev,
                            const int* __restrict__ ey, const int* __restrict__ nu,
                            const int* __restrict__ nv, const int* __restrict__ ny,
                            int* __restrict__ cursor, int* __restrict__ csr_e,
                            int* __restrict__ csr_s, int* __restrict__ csr_h) {
    int gid = blockIdx.x * blockDim.x + threadIdx.x;
    if (gid >= 450000) return;
    int p = gid / 150000;
    int r = gid - p * 150000;
    const int* e = (p == 0) ? eu : (p == 1) ? ev : ey;
    const int* nx = (p == 0) ? nu : (p == 1) ? nv : ny;
    if (r < N_EDGES) {
        int d = e[N_EDGES + r];
        int pos = atomicAdd(&cursor[p * 30000 + d], 1);
        csr_e[p * N_EDGES + pos] = e[r];
    } else if (r < N_EDGES + N_SPS) {
        int i = r - N_EDGES;
        int spid = nx[N_SPS + i];
        int pos = atomicAdd(&cursor[(3 + p) * 30000 + spid], 1);
        csr_s[p * N_SPS + pos] = nx[i];
    } else {
        int i = r - N_EDGES - N_SPS;
        int hit = nx[i];
        int pos = atomicAdd(&cursor[(6 + p) * 30000 + hit], 1);
        csr_h[p * N_SPS + pos] = nx[N_SPS + i];
    }
}

// ---------------- weight pre-pack (f16) ----------------
__device__ __forceinline__ void pack4(const float* __restrict__ W, _Float16* __restrict__ P,
                                      int idx, int koff) {
    int j = idx & 7, lane = (idx >> 3) & 63, ks = (idx >> 9) & 3, n = (idx >> 11) & 7;
    int k = ks * 32 + (lane >> 4) * 8 + j, col = n * 16 + (lane & 15);
    P[idx] = (_Float16)W[(k + koff) * 128 + col];
}
__device__ __forceinline__ void pack8(const float* __restrict__ W, _Float16* __restrict__ P, int idx) {
    int j = idx & 7, lane = (idx >> 3) & 63, ks = (idx >> 9) & 7, n = (idx >> 12) & 7;
    int k = ks * 32 + (lane >> 4) * 8 + j, col = n * 16 + (lane & 15);
    P[idx] = (_Float16)W[k * 128 + col];
}

__global__ void wprep_kernel(const float* __restrict__ W1, const float* __restrict__ W2,
                             const float* __restrict__ Wu, const float* __restrict__ Wn,
                             const float* __restrict__ Wsp, _Float16* __restrict__ packs) {
    int gid = blockIdx.x * blockDim.x + threadIdx.x;
    if (gid < 16384) { pack4(W1, packs, gid, 0); return; }            // W1d
    gid -= 16384;
    if (gid < 16384) { pack4(W1, packs + 16384, gid, 128); return; }  // W1s
    gid -= 16384;
    if (gid < 16384) { pack4(W2, packs + 32768, gid, 0); return; }    // W2
    gid -= 16384;
    if (gid < 32768) { pack8(Wu, packs + 49152, gid); return; }       // W_upd
    gid -= 32768;
    if (gid < 32768) { pack8(Wn, packs + 81920, gid); return; }       // W_nx
    gid -= 32768;
    if (gid < 16384) { pack4(Wsp, packs + 114688, gid, 0); }          // W_sp
}

// ---------------- fused encoder + y emission ----------------
__launch_bounds__(256, 4)
__global__ void enc_y_kernel(const float* __restrict__ xu, const float* __restrict__ xv,
                             const float* __restrict__ xy, const float* __restrict__ We,
                             const float* __restrict__ be, const _Float16* __restrict__ W1dP,
                             const _Float16* __restrict__ W1sP, _Float16* __restrict__ h,
                             _Float16* __restrict__ y_d, _Float16* __restrict__ y_s) {
    __shared__ _Float16 sA[128 * PADM];
    __shared__ _Float16 sO[128 * PADM];
    int t = threadIdx.x;
    int n0b = blockIdx.x * 128;
    const int M = 3 * N_HITS;
    for (int i = t; i < 2048; i += 256) {
        int row = i >> 4, c = i & 15;
        int n = n0b + row; if (n >= M) n = M - 1;
        int p = n / N_HITS;
        int nn = n - p * N_HITS;
        const float* x = (p == 0) ? xu : (p == 1) ? xv : xy;
        float4 xv4 = *(const float4*)(x + nn * 4);
        union { _Float16 o8[8]; uint4 u; } outv;
#pragma unroll
        for (int j = 0; j < 8; ++j) {
            int col = c * 8 + j;
            float acc = be[col];
            acc = fmaf(xv4.x, We[0 * HD + col], acc);
            acc = fmaf(xv4.y, We[1 * HD + col], acc);
            acc = fmaf(xv4.z, We[2 * HD + col], acc);
            acc = fmaf(xv4.w, We[3 * HD + col], acc);
            outv.o8[j] = (_Float16)fmaxf(acc, 0.f);
        }
        *(uint4*)&sA[row * PADM + c * 8] = outv.u;
        if (n0b + row < M) ((uint4*)(h + (size_t)n * HD))[c] = outv.u;
    }
    __syncthreads();

    int lane = t & 63, wave = t >> 6;
    int lcol = lane & 15, quad = lane >> 4;
    int nt0 = wave * 2;
    bool odd = (lcol & 1) != 0;

    for (int half = 0; half < 2; ++half) {
        const f16x8* wp = (const f16x8*)(half == 0 ? W1dP : W1sP);
        _Float16* out = half == 0 ? y_d : y_s;
        f16x8 B[2][4];
#pragma unroll
        for (int nt = 0; nt < 2; ++nt)
#pragma unroll
            for (int ks = 0; ks < 4; ++ks)
                B[nt][ks] = wp[((nt0 + nt) * 4 + ks) * 64 + lane];
        floatx4 acc[8][2];
#pragma unroll
        for (int mt = 0; mt < 8; ++mt) { acc[mt][0] = (floatx4){0,0,0,0}; acc[mt][1] = (floatx4){0,0,0,0}; }
#pragma unroll
        for (int mt = 0; mt < 8; ++mt)
#pragma unroll
            for (int ks = 0; ks < 4; ++ks) {
                f16x8 a = *(const f16x8*)&sA[(mt * 16 + lcol) * PADM + ks * 32 + quad * 8];
                acc[mt][0] = __builtin_amdgcn_mfma_f32_16x16x32_f16(a, B[0][ks], acc[mt][0], 0, 0, 0);
                acc[mt][1] = __builtin_amdgcn_mfma_f32_16x16x32_f16(a, B[1][ks], acc[mt][1], 0, 0, 0);
            }
#pragma unroll
        for (int mt = 0; mt < 8; ++mt)
#pragma unroll
            for (int r = 0; r < 4; ++r) {
                float v0 = acc[mt][0][r], v1 = acc[mt][1][r];
                float p0 = __shfl_xor(v0, 1), p1 = __shfl_xor(v1, 1);
                float av = odd ? p1 : v0, bv = odd ? v1 : p0;
                int col = nt0 * 16 + (odd ? 15 + lcol : lcol);
                *(uint*)&sO[(mt * 16 + quad * 4 + r) * PADM + col] = f2h2(av, bv);
            }
        __syncthreads();
        for (int i = t; i < 2048; i += 256) {
            int row = i >> 4, c = i & 15;
            int n = n0b + row;
            if (n < M) ((uint4*)(out + (size_t)n * HD))[c] = *(uint4*)&sO[row * PADM + c * 8];
        }
        __syncthreads();
    }
}

// ---------------- planar update, M=64, single LDS buffer, 4-peel gather ----------------
#define ECAP 640
__launch_bounds__(256, 5)
__global__ void update_planar_kernel(_Float16* __restrict__ h, const _Float16* __restrict__ y_d,
                                     const _Float16* __restrict__ y_s,
                                     const int* __restrict__ off, const int* __restrict__ csr_e,
                                     const float* __restrict__ b1,
                                     const _Float16* __restrict__ W2P, const float* __restrict__ b2,
                                     const _Float16* __restrict__ WuP, const float* __restrict__ bu) {
    int p = blockIdx.y;
    _Float16* hp = h + (size_t)p * N_HITS * HD;
    const _Float16* ydp = y_d + (size_t)p * N_HITS * HD;
    const _Float16* ysp = y_s + (size_t)p * N_HITS * HD;
    const int* o = off + p * 30001;
    const int* csr = csr_e + p * N_EDGES;

    __shared__ _Float16 sA[64 * PADM];
    __shared__ int sOff[65];
    __shared__ int sIdx[ECAP];
    int t = threadIdx.x;
    int n0b = blockIdx.x * 64;
    int lane = t & 63, wave = t >> 6;
    int lcol = lane & 15, quad = lane >> 4;
    int nt0 = wave * 2;
    bool odd = (lcol & 1) != 0;

    if (t < 65) {
        int idx = n0b + t; if (idx > N_HITS) idx = N_HITS;
        sOff[t] = o[idx];
    }
    for (int i = t; i < 1024; i += 256) {
        int row = i >> 4, c = i & 15;
        int n = n0b + row; if (n >= N_HITS) n = N_HITS - 1;
        f16x8 yv = *(const f16x8*)&ydp[(size_t)n * HD + c * 8];
        float4 b1a = *(const float4*)(b1 + c * 8);
        float4 b1b = *(const float4*)(b1 + c * 8 + 4);
        float bb[8] = {b1a.x, b1a.y, b1a.z, b1a.w, b1b.x, b1b.y, b1b.z, b1b.w};
        f16x8 ov;
#pragma unroll
        for (int j = 0; j < 8; ++j) ov[j] = (_Float16)((float)yv[j] + bb[j]);
        *(f16x8*)&sA[row * PADM + c * 8] = ov;
    }
    __syncthreads();
    int base = sOff[0];
    int total = sOff[64] - base;
    bool useL = (total <= ECAP);
    if (useL) for (int i = t; i < total; i += 256) sIdx[i] = csr[base + i];
    __syncthreads();

    // phase A: in-place CSR edge gather, 4-peel + 2-way loop
    for (int i = t; i < 1024; i += 256) {
        int row = i >> 4, c = i & 15;
        int d = n0b + row;
        int beg = 0, end = 0;
        if (d < N_HITS) { beg = sOff[row]; end = sOff[row + 1]; }
        f16x8 ydv = *(const f16x8*)&sA[row * PADM + c * 8];
        f16x8 a0 = (f16x8)(_Float16)0, a1 = (f16x8)(_Float16)0;
        f16x8 a2 = (f16x8)(_Float16)0, a3 = (f16x8)(_Float16)0;
        int k = beg;
        int rem = end - beg;
        if (rem > 0) {
            int s0 = useL ? sIdx[k - base] : csr[k];
            int s1 = (rem > 1) ? (useL ? sIdx[k + 1 - base] : csr[k + 1]) : s0;
            int s2 = (rem > 2) ? (useL ? sIdx[k + 2 - base] : csr[k + 2]) : s0;
            int s3 = (rem > 3) ? (useL ? sIdx[k + 3 - base] : csr[k + 3]) : s0;
            f16x8 v0 = *(const f16x8*)&ysp[(size_t)s0 * HD + c * 8];
            f16x8 v1 = *(const f16x8*)&ysp[(size_t)s1 * HD + c * 8];
            f16x8 v2 = *(const f16x8*)&ysp[(size_t)s2 * HD + c * 8];
            f16x8 v3 = *(const f16x8*)&ysp[(size_t)s3 * HD + c * 8];
            a0 += __builtin_elementwise_max(v0 + ydv, (f16x8)(_Float16)0);
            if (rem > 1) a1 += __builtin_elementwise_max(v1 + ydv, (f16x8)(_Float16)0);
            if (rem > 2) a2 += __builtin_elementwise_max(v2 + ydv, (f16x8)(_Float16)0);
            if (rem > 3) a3 += __builtin_elementwise_max(v3 + ydv, (f16x8)(_Float16)0);
            k += (rem < 4) ? rem : 4;
        }
        for (; k + 2 <= end; k += 2) {
            int s0 = useL ? sIdx[k - base] : csr[k];
            int s1 = useL ? sIdx[k + 1 - base] : csr[k + 1];
            f16x8 v0 = *(const f16x8*)&ysp[(size_t)s0 * HD + c * 8];
            f16x8 v1 = *(const f16x8*)&ysp[(size_t)s1 * HD + c * 8];
            a0 += __builtin_elementwise_max(v0 + ydv, (f16x8)(_Float16)0);
            a1 += __builtin_elementwise_max(v1 + ydv, (f16x8)(_Float16)0);
        }
        if (k < end) {
            int s0 = useL ? sIdx[k - base] : csr[k];
            f16x8 v0 = *(const f16x8*)&ysp[(size_t)s0 * HD + c * 8];
            a0 += __builtin_elementwise_max(v0 + ydv, (f16x8)(_Float16)0);
        }
        f16x8 accv = (a0 + a1) + (a2 + a3);
        _Float16 iv = (_Float16)((end > beg) ? 1.f / (float)(end - beg) : 0.f);
        accv *= iv;
        *(f16x8*)&sA[row * PADM + c * 8] = accv;
    }
    __syncthreads();
    // phase B: agg = z @ W2 + b2
    floatx4 acc[4][2];
    {
        const f16x8* w2p = (const f16x8*)W2P;
        f16x8 B[2][4];
#pragma unroll
        for (int nt = 0; nt < 2; ++nt)
#pragma unroll
            for (int ks = 0; ks < 4; ++ks)
                B[nt][ks] = w2p[((nt0 + nt) * 4 + ks) * 64 + lane];
#pragma unroll
        for (int nt = 0; nt < 2; ++nt) {
            float bv = b2[(nt0 + nt) * 16 + lcol];
#pragma unroll
            for (int mt = 0; mt < 4; ++mt) acc[mt][nt] = (floatx4){bv, bv, bv, bv};
        }
#pragma unroll
        for (int mt = 0; mt < 4; ++mt)
#pragma unroll
            for (int ks = 0; ks < 4; ++ks) {
                f16x8 a = *(const f16x8*)&sA[(mt * 16 + lcol) * PADM + ks * 32 + quad * 8];
                acc[mt][0] = __builtin_amdgcn_mfma_f32_16x16x32_f16(a, B[0][ks], acc[mt][0], 0, 0, 0);
                acc[mt][1] = __builtin_amdgcn_mfma_f32_16x16x32_f16(a, B[1][ks], acc[mt][1], 0, 0, 0);
            }
    }
    __syncthreads();
    // phase C: agg -> sA
#pragma unroll
    for (int mt = 0; mt < 4; ++mt)
#pragma unroll
        for (int r = 0; r < 4; ++r) {
            float v0 = acc[mt][0][r], v1 = acc[mt][1][r];
            float p0 = __shfl_xor(v0, 1), p1 = __shfl_xor(v1, 1);
            float av = odd ? p1 : v0, bv = odd ? v1 : p0;
            int col = nt0 * 16 + (odd ? 15 + lcol : lcol);
            *(uint*)&sA[(mt * 16 + quad * 4 + r) * PADM + col] = f2h2(av, bv);
        }
    __syncthreads();
    // phase D: accU = bu + agg @ Wu[ks4..7]
    {
        const f16x8* wu = (const f16x8*)WuP;
        f16x8 B[2][4];
#pragma unroll
        for (int nt = 0; nt < 2; ++nt)
#pragma unroll
            for (int ks = 0; ks < 4; ++ks)
                B[nt][ks] = wu[((nt0 + nt) * 8 + 4 + ks) * 64 + lane];
        floatx4 tmp[4][2];
#pragma unroll
        for (int nt = 0; nt < 2; ++nt) {
            float bv = bu[(nt0 + nt) * 16 + lcol];
#pragma unroll
            for (int mt = 0; mt < 4; ++mt) tmp[mt][nt] = (floatx4){bv, bv, bv, bv};
        }
#pragma unroll
        for (int mt = 0; mt < 4; ++mt)
#pragma unroll
            for (int ks = 0; ks < 4; ++ks) {
                f16x8 a = *(const f16x8*)&sA[(mt * 16 + lcol) * PADM + ks * 32 + quad * 8];
                tmp[mt][0] = __builtin_amdgcn_mfma_f32_16x16x32_f16(a, B[0][ks], tmp[mt][0], 0, 0, 0);
                tmp[mt][1] = __builtin_amdgcn_mfma_f32_16x16x32_f16(a, B[1][ks], tmp[mt][1], 0, 0, 0);
            }
#pragma unroll
        for (int mt = 0; mt < 4; ++mt) { acc[mt][0] = tmp[mt][0]; acc[mt][1] = tmp[mt][1]; }
    }
    __syncthreads();
    // phase E: stage h -> sA
    for (int i = t; i < 1024; i += 256) {
        int row = i >> 4, c = i & 15;
        int n = n0b + row; if (n >= N_HITS) n = N_HITS - 1;
        *(uint4*)&sA[row * PADM + c * 8] = ((const uint4*)(hp + (size_t)n * HD))[c];
    }
    __syncthreads();
    // phase F: accU += h @ Wu[ks0..3]
    {
        const f16x8* wu = (const f16x8*)WuP;
        f16x8 B[2][4];
#pragma unroll
        for (int nt = 0; nt < 2; ++nt)
#pragma unroll
            for (int ks = 0; ks < 4; ++ks)
                B[nt][ks] = wu[((nt0 + nt) * 8 + ks) * 64 + lane];
#pragma unroll
        for (int mt = 0; mt < 4; ++mt)
#pragma unroll
            for (int ks = 0; ks < 4; ++ks) {
                f16x8 a = *(const f16x8*)&sA[(mt * 16 + lcol) * PADM + ks * 32 + quad * 8];
                acc[mt][0] = __builtin_amdgcn_mfma_f32_16x16x32_f16(a, B[0][ks], acc[mt][0], 0, 0, 0);
                acc[mt][1] = __builtin_amdgcn_mfma_f32_16x16x32_f16(a, B[1][ks], acc[mt][1], 0, 0, 0);
            }
    }
    __syncthreads();
    // phase G: h_new = h(sA) + relu(accU) -> sA
#pragma unroll
    for (int mt = 0; mt < 4; ++mt)
#pragma unroll
        for (int r = 0; r < 4; ++r) {
            float v0 = fmaxf(acc[mt][0][r], 0.f), v1 = fmaxf(acc[mt][1][r], 0.f);
            float p0 = __shfl_xor(v0, 1), p1 = __shfl_xor(v1, 1);
            float av = odd ? p1 : v0, bv = odd ? v1 : p0;
            int col = nt0 * 16 + (odd ? 15 + lcol : lcol);
            uint* sp2 = (uint*)&sA[(mt * 16 + quad * 4 + r) * PADM + col];
            float2 ho = h2f2(*sp2);
            *sp2 = f2h2(ho.x + av, ho.y + bv);
        }
    __syncthreads();
    // phase H: coalesced store sA -> h
    for (int i = t; i < 1024; i += 256) {
        int row = i >> 4, c = i & 15;
        int n = n0b + row;
        if (n < N_HITS) ((uint4*)(hp + (size_t)n * HD))[c] = *(uint4*)&sA[row * PADM + c * 8];
    }
}

// ---------------- sp fused (M=64), 2-peel 3-plane gather ----------------
#define SCAP 576
__launch_bounds__(256, 6)
__global__ void sp_fused_kernel(const _Float16* __restrict__ h, const int* __restrict__ off,
                                const int* __restrict__ csr_s, const _Float16* __restrict__ WspP,
                                const float* __restrict__ b, _Float16* __restrict__ spf) {
    __shared__ _Float16 sA[64 * PADM];
    __shared__ int sOff[3][65];
    __shared__ int sIdx[SCAP];
    int t = threadIdx.x;
    int n0b = blockIdx.x * 64;
    int lane = t & 63, wave = t >> 6;
    int lcol = lane & 15, quad = lane >> 4;
    int nt0 = wave * 2;
    bool odd = (lcol & 1) != 0;

    if (t < 195) {
        int p = t / 65, i = t - p * 65;
        int idx = n0b + i; if (idx > N_SPS) idx = N_SPS;
        sOff[p][i] = off[(3 + p) * 30001 + idx];
    }
    __syncthreads();
    int base0 = sOff[0][0], len0 = sOff[0][64] - base0;
    int base1 = sOff[1][0], len1 = sOff[1][64] - base1;
    int base2 = sOff[2][0], len2 = sOff[2][64] - base2;
    int ofs1 = len0, ofs2 = len0 + len1;
    bool useL = (ofs2 + len2 <= SCAP);
    if (useL) {
        for (int i = t; i < len0; i += 256) sIdx[i] = csr_s[base0 + i];
        for (int i = t; i < len1; i += 256) sIdx[ofs1 + i] = csr_s[N_SPS + base1 + i];
        for (int i = t; i < len2; i += 256) sIdx[ofs2 + i] = csr_s[2 * N_SPS + base2 + i];
    }
    __syncthreads();

    for (int i = t; i < 1024; i += 256) {
        int row = i >> 4, c = i & 15;
        int s = n0b + row;
        f16x8 tv = (f16x8)(_Float16)0;
        if (s < N_SPS) {
#pragma unroll
            for (int p = 0; p < 3; ++p) {
                int beg = sOff[p][row], end = sOff[p][row + 1];
                int bb = (p == 0) ? base0 : (p == 1) ? base1 : base2;
                int oo = (p == 0) ? 0 : (p == 1) ? ofs1 : ofs2;
                const int* csr = csr_s + p * N_SPS;
                const _Float16* hb = h + (size_t)p * N_HITS * HD;
                f16x8 s0v = (f16x8)(_Float16)0, s1v = (f16x8)(_Float16)0;
                int k = beg;
                int rem = end - beg;
                if (rem > 0) {
                    int h0 = useL ? sIdx[oo + (k - bb)] : csr[k];
                    int h1 = (rem > 1) ? (useL ? sIdx[oo + (k + 1 - bb)] : csr[k + 1]) : h0;
                    f16x8 v0 = *(const f16x8*)&hb[(size_t)h0 * HD + c * 8];
                    f16x8 v1 = *(const f16x8*)&hb[(size_t)h1 * HD + c * 8];
                    s0v += v0;
                    if (rem > 1) s1v += v1;
                    k += (rem < 2) ? rem : 2;
                }
                for (; k + 2 <= end; k += 2) {
                    int h0 = useL ? sIdx[oo + (k - bb)] : csr[k];
                    int h1 = useL ? sIdx[oo + (k + 1 - bb)] : csr[k + 1];
                    f16x8 v0 = *(const f16x8*)&hb[(size_t)h0 * HD + c * 8];
                    f16x8 v1 = *(const f16x8*)&hb[(size_t)h1 * HD + c * 8];
                    s0v += v0; s1v += v1;
                }
                if (k < end) {
                    int h0 = useL ? sIdx[oo + (k - bb)] : csr[k];
                    s0v += *(const f16x8*)&hb[(size_t)h0 * HD + c * 8];
                }
                f16x8 sv = s0v + s1v;
                _Float16 iv = (_Float16)((end > beg) ? 1.f / (float)(end - beg) : 0.f);
                tv += sv * iv;
            }
        }
        *(f16x8*)&sA[row * PADM + c * 8] = tv;
    }
    __syncthreads();

    const f16x8* wp = (const f16x8*)WspP;
    f16x8 B[2][4];
#pragma unroll
    for (int nt = 0; nt < 2; ++nt)
#pragma unroll
        for (int ks = 0; ks < 4; ++ks)
            B[nt][ks] = wp[((nt0 + nt) * 4 + ks) * 64 + lane];

    floatx4 acc[4][2];
#pragma unroll
    for (int nt = 0; nt < 2; ++nt) {
        float bv = b[(nt0 + nt) * 16 + lcol];
#pragma unroll
        for (int mt = 0; mt < 4; ++mt) acc[mt][nt] = (floatx4){bv, bv, bv, bv};
    }
#pragma unroll
    for (int mt = 0; mt < 4; ++mt)
#pragma unroll
        for (int ks = 0; ks < 4; ++ks) {
            f16x8 a = *(const f16x8*)&sA[(mt * 16 + lcol) * PADM + ks * 32 + quad * 8];
            acc[mt][0] = __builtin_amdgcn_mfma_f32_16x16x32_f16(a, B[0][ks], acc[mt][0], 0, 0, 0);
            acc[mt][1] = __builtin_amdgcn_mfma_f32_16x16x32_f16(a, B[1][ks], acc[mt][1], 0, 0, 0);
        }
    __syncthreads();
#pragma unroll
    for (int mt = 0; mt < 4; ++mt)
#pragma unroll
        for (int r = 0; r < 4; ++r) {
            float v0 = fmaxf(acc[mt][0][r], 0.f), v1 = fmaxf(acc[mt][1][r], 0.f);
            float p0 = __shfl_xor(v0, 1), p1 = __shfl_xor(v1, 1);
            float av = odd ? p1 : v0, bv = odd ? v1 : p0;
            int col = nt0 * 16 + (odd ? 15 + lcol : lcol);
            *(uint*)&sA[(mt * 16 + quad * 4 + r) * PADM + col] = f2h2(av, bv);
        }
    __syncthreads();
    for (int i = t; i < 1024; i += 256) {
        int row = i >> 4, c = i & 15;
        int n = n0b + row;
        if (n < N_SPS) ((uint4*)(spf + (size_t)n * HD))[c] = *(uint4*)&sA[row * PADM + c * 8];
    }
}

// ---------------- nexus update (M=64); last iter: skip y GEMMs, fuse decoder ----------------
#define HCAP 320
__launch_bounds__(256, 4)
__global__ void update_y_kernel(_Float16* __restrict__ h, const _Float16* __restrict__ sp,
                                const int* __restrict__ off, const int* __restrict__ csr_h,
                                const _Float16* __restrict__ WP, const float* __restrict__ b,
                                const _Float16* __restrict__ W1dP, const _Float16* __restrict__ W1sP,
                                _Float16* __restrict__ y_d, _Float16* __restrict__ y_s,
                                const float* __restrict__ Wsem, const float* __restrict__ bsem,
                                float* __restrict__ out, int last) {
    int p = blockIdx.y;
    _Float16* hp = h + (size_t)p * N_HITS * HD;
    _Float16* ydp = y_d + (size_t)p * N_HITS * HD;
    _Float16* ysp = y_s + (size_t)p * N_HITS * HD;
    const int* o = off + (6 + p) * 30001;
    const int* csr = csr_h + p * N_SPS;

    __shared__ _Float16 sH[64 * PADM];
    __shared__ _Float16 sA[64 * PADM];
    __shared__ int sOff[65];
    __shared__ int sIdx[HCAP];
    int t = threadIdx.x;
    int n0b = blockIdx.x * 64;
    int lane = t & 63, wave = t >> 6;
    int lcol = lane & 15, quad = lane >> 4;
    int nt0 = wave * 2;
    bool odd = (lcol & 1) != 0;

    if (t < 65) {
        int idx = n0b + t; if (idx > N_HITS) idx = N_HITS;
        sOff[t] = o[idx];
    }
    for (int i = t; i < 1024; i += 256) {
        int row = i >> 4, c = i & 15;
        int n = n0b + row; if (n >= N_HITS) n = N_HITS - 1;
        *(uint4*)&sH[row * PADM + c * 8] = ((const uint4*)(hp + (size_t)n * HD))[c];
    }
    __syncthreads();
    int base = sOff[0];
    int total = sOff[64] - base;
    bool useL = (total <= HCAP);
    if (useL) for (int i = t; i < total; i += 256) sIdx[i] = csr[base + i];
    __syncthreads();

    // phase A: gather aux -> sA (2-peel + 2-way)
    for (int i = t; i < 1024; i += 256) {
        int row = i >> 4, c = i & 15;
        int hit = n0b + row;
        int beg = 0, end = 0;
        if (hit < N_HITS) { beg = sOff[row]; end = sOff[row + 1]; }
        f16x8 a0 = (f16x8)(_Float16)0, a1 = (f16x8)(_Float16)0;
        int k = beg;
        int rem = end - beg;
        if (rem > 0) {
            int s0 = useL ? sIdx[k - base] : csr[k];
            int s1 = (rem > 1) ? (useL ? sIdx[k + 1 - base] : csr[k + 1]) : s0;
            f16x8 v0 = *(const f16x8*)&sp[(size_t)s0 * HD + c * 8];
            f16x8 v1 = *(const f16x8*)&sp[(size_t)s1 * HD + c * 8];
            a0 += v0;
            if (rem > 1) a1 += v1;
            k += (rem < 2) ? rem : 2;
        }
        for (; k + 2 <= end; k += 2) {
            int s0 = useL ? sIdx[k - base] : csr[k];
            int s1 = useL ? sIdx[k + 1 - base] : csr[k + 1];
            f16x8 v0 = *(const f16x8*)&sp[(size_t)s0 * HD + c * 8];
            f16x8 v1 = *(const f16x8*)&sp[(size_t)s1 * HD + c * 8];
            a0 += v0; a1 += v1;
        }
        if (k < end) {
            int s0 = useL ? sIdx[k - base] : csr[k];
            a0 += *(const f16x8*)&sp[(size_t)s0 * HD + c * 8];
        }
        f16x8 av8 = a0 + a1;
        _Float16 iv = (_Float16)((end > beg) ? 1.f / (float)(end - beg) : 0.f);
        av8 *= iv;
        *(f16x8*)&sA[row * PADM + c * 8] = av8;
    }
    __syncthreads();
    // phase B: acc = b + sH@Wn[ks0..3] + sA@Wn[ks4..7]
    floatx4 acc[4][2];
    {
        const f16x8* wp = (const f16x8*)WP;
        f16x8 BH[2][4], BA[2][4];
#pragma unroll
        for (int nt = 0; nt < 2; ++nt)
#pragma unroll
            for (int ks = 0; ks < 4; ++ks) {
                BH[nt][ks] = wp[((nt0 + nt) * 8 + ks) * 64 + lane];
                BA[nt][ks] = wp[((nt0 + nt) * 8 + 4 + ks) * 64 + lane];
            }
#pragma unroll
        for (int nt = 0; nt < 2; ++nt) {
            float bv = b[(nt0 + nt) * 16 + lcol];
#pragma unroll
            for (int mt = 0; mt < 4; ++mt) acc[mt][nt] = (floatx4){bv, bv, bv, bv};
        }
#pragma unroll
        for (int mt = 0; mt < 4; ++mt)
#pragma unroll
            for (int ks = 0; ks < 4; ++ks) {
                f16x8 ah = *(const f16x8*)&sH[(mt * 16 + lcol) * PADM + ks * 32 + quad * 8];
                f16x8 aa = *(const f16x8*)&sA[(mt * 16 + lcol) * PADM + ks * 32 + quad * 8];
                acc[mt][0] = __builtin_amdgcn_mfma_f32_16x16x32_f16(ah, BH[0][ks], acc[mt][0], 0, 0, 0);
                acc[mt][1] = __builtin_amdgcn_mfma_f32_16x16x32_f16(ah, BH[1][ks], acc[mt][1], 0, 0, 0);
                acc[mt][0] = __builtin_amdgcn_mfma_f32_16x16x32_f16(aa, BA[0][ks], acc[mt][0], 0, 0, 0);
                acc[mt][1] = __builtin_amdgcn_mfma_f32_16x16x32_f16(aa, BA[1][ks], acc[mt][1], 0, 0, 0);
            }
    }
    __syncthreads();
    // phase C: h_new = sH + relu(acc) -> sH
#pragma unroll
    for (int mt = 0; mt < 4; ++mt)
#pragma unroll
        for (int r = 0; r < 4; ++r) {
            float v0 = fmaxf(acc[mt][0][r], 0.f), v1 = fmaxf(acc[mt][1][r], 0.f);
            float p0 = __shfl_xor(v0, 1), p1 = __shfl_xor(v1, 1);
            float av = odd ? p1 : v0, bv = odd ? v1 : p0;
            int col = nt0 * 16 + (odd ? 15 + lcol : lcol);
            uint* sp2 = (uint*)&sH[(mt * 16 + quad * 4 + r) * PADM + col];
            float2 ho = h2f2(*sp2);
            *sp2 = f2h2(ho.x + av, ho.y + bv);
        }
    __syncthreads();
    // phase D: coalesced h store
    for (int i = t; i < 1024; i += 256) {
        int row = i >> 4, c = i & 15;
        int n = n0b + row;
        if (n < N_HITS) ((uint4*)(hp + (size_t)n * HD))[c] = *(uint4*)&sH[row * PADM + c * 8];
    }
    if (last) {
        // fused decoder: out[n] = h_new @ Wsem + bsem; 4 threads/row, 32 cols each
        int row = t >> 2, part = t & 3;
        int n = n0b + row;
        float a0 = 0.f, a1 = 0.f, a2 = 0.f, a3 = 0.f, a4 = 0.f;
        const _Float16* hr = &sH[row * PADM + part * 32];
#pragma unroll
        for (int q = 0; q < 4; ++q) {
            f16x8 v = *(const f16x8*)(hr + q * 8);
#pragma unroll
            for (int j = 0; j < 8; ++j) {
                float x = (float)v[j];
                const float* w = Wsem + (part * 32 + q * 8 + j) * NCLS;
                a0 = fmaf(x, w[0], a0);
                a1 = fmaf(x, w[1], a1);
                a2 = fmaf(x, w[2], a2);
                a3 = fmaf(x, w[3], a3);
                a4 = fmaf(x, w[4], a4);
            }
        }
        a0 += __shfl_xor(a0, 1); a0 += __shfl_xor(a0, 2);
        a1 += __shfl_xor(a1, 1); a1 += __shfl_xor(a1, 2);
        a2 += __shfl_xor(a2, 1); a2 += __shfl_xor(a2, 2);
        a3 += __shfl_xor(a3, 1); a3 += __shfl_xor(a3, 2);
        a4 += __shfl_xor(a4, 1); a4 += __shfl_xor(a4, 2);
        if (part == 0 && n < N_HITS) {
            float* oo = out + ((size_t)p * N_HITS + n) * NCLS;
            oo[0] = a0 + bsem[0]; oo[1] = a1 + bsem[1]; oo[2] = a2 + bsem[2];
            oo[3] = a3 + bsem[3]; oo[4] = a4 + bsem[4];
        }
        return;
    }
    // phase E: y GEMMs from sH
    for (int half = 0; half < 2; ++half) {
        const f16x8* wyp = (const f16x8*)(half == 0 ? W1sP : W1dP);
        _Float16* outy = half == 0 ? ysp : ydp;
        f16x8 B[2][4];
#pragma unroll
        for (int nt = 0; nt < 2; ++nt)
#pragma unroll
            for (int ks = 0; ks < 4; ++ks)
                B[nt][ks] = wyp[((nt0 + nt) * 4 + ks) * 64 + lane];
        floatx4 yacc[4][2];
#pragma unroll
        for (int mt = 0; mt < 4; ++mt) { yacc[mt][0] = (floatx4){0,0,0,0}; yacc[mt][1] = (floatx4){0,0,0,0}; }
#pragma unroll
        for (int mt = 0; mt < 4; ++mt)
#pragma unroll
            for (int ks = 0; ks < 4; ++ks) {
                f16x8 a = *(const f16x8*)&sH[(mt * 16 + lcol) * PADM + ks * 32 + quad * 8];
                yacc[mt][0] = __builtin_amdgcn_mfma_f32_16x16x32_f16(a, B[0][ks], yacc[mt][0], 0, 0, 0);
                yacc[mt][1] = __builtin_amdgcn_mfma_f32_16x16x32_f16(a, B[1][ks], yacc[mt][1], 0, 0, 0);
            }
        __syncthreads();
#pragma unroll
        for (int mt = 0; mt < 4; ++mt)
#pragma unroll
            for (int r = 0; r < 4; ++r) {
                float v0 = yacc[mt][0][r], v1 = yacc[mt][1][r];
                float p0 = __shfl_xor(v0, 1), p1 = __shfl_xor(v1, 1);
                float av = odd ? p1 : v0, bv = odd ? v1 : p0;
                int col = nt0 * 16 + (odd ? 15 + lcol : lcol);
                *(uint*)&sA[(mt * 16 + quad * 4 + r) * PADM + col] = f2h2(av, bv);
            }
        __syncthreads();
        for (int i = t; i < 1024; i += 256) {
            int row = i >> 4, c = i & 15;
            int n = n0b + row;
            if (n < N_HITS) ((uint4*)(outy + (size_t)n * HD))[c] = *(uint4*)&sA[row * PADM + c * 8];
        }
    }
}

extern "C" void kernel_launch(void* const* d_in, const int* in_sizes, int n_in,
                              void* d_out, int out_size, void* d_ws, size_t ws_size,
                              hipStream_t stream) {
    const float* xu = (const float*)d_in[0];
    const int* eu = (const int*)d_in[1];
    const int* nu = (const int*)d_in[2];
    const float* xv = (const float*)d_in[3];
    const int* ev = (const int*)d_in[4];
    const int* nv = (const int*)d_in[5];
    const float* xy = (const float*)d_in[6];
    const int* ey = (const int*)d_in[7];
    const int* ny = (const int*)d_in[8];
    const float* W_enc = (const float*)d_in[9];
    const float* b_enc = (const float*)d_in[10];
    const float* W1 = (const float*)d_in[11];
    const float* b1 = (const float*)d_in[12];
    const float* W2 = (const float*)d_in[13];
    const float* b2 = (const float*)d_in[14];
    const float* W_upd = (const float*)d_in[15];
    const float* b_upd = (const float*)d_in[16];
    const float* W_sp = (const float*)d_in[17];
    const float* b_sp = (const float*)d_in[18];
    const float* W_nx = (const float*)d_in[19];
    const float* b_nx = (const float*)d_in[20];
    const float* W_sem = (const float*)d_in[21];
    const float* b_sem = (const float*)d_in[22];

    const size_t HN = (size_t)3 * N_HITS * HD;
    _Float16* h = (_Float16*)d_ws;                 // f16 [3][N_HITS][HD]
    _Float16* y_s = h + HN;                        // f16 [3][N_HITS][HD]
    _Float16* y_d = y_s + HN;                      // f16 [3][N_HITS][HD]
    _Float16* sp = y_d + HN;                       // f16 [N_SPS][HD]
    int* cnt = (int*)(sp + (size_t)N_SPS * HD);    // [270000]
    int* off = cnt + 270000;                       // [9*30001]
    int* cursor = off + 270009;                    // [270000]
    int* csr_e = cursor + 270000;                  // [3*90000]
    int* csr_s = csr_e + 270000;                   // [3*30000]
    int* csr_h = csr_s + 90000;                    // [3*30000]
    _Float16* packs = (_Float16*)(csr_h + 90000);  // [131072]
    _Float16* W1dP = packs;
    _Float16* W1sP = packs + 16384;
    _Float16* W2P = packs + 32768;
    _Float16* WuP = packs + 49152;
    _Float16* WnP = packs + 81920;
    _Float16* WspP = packs + 114688;

    wprep_kernel<<<512, 256, 0, stream>>>(W1, W2, W_upd, W_nx, W_sp, packs);
    (void)hipMemsetAsync(cnt, 0, 270000 * sizeof(int), stream);
    hist_all_kernel<<<(450000 + 255) / 256, 256, 0, stream>>>(eu, ev, ey, nu, nv, ny, cnt);
    scan_kernel<<<9, 1024, 0, stream>>>(cnt, off, cursor);
    fill_kernel<<<(450000 + 255) / 256, 256, 0, stream>>>(eu, ev, ey, nu, nv, ny,
                                                          cursor, csr_e, csr_s, csr_h);

    enc_y_kernel<<<(3 * N_HITS + 127) / 128, 256, 0, stream>>>(xu, xv, xy, W_enc, b_enc,
                                                               W1dP, W1sP, h, y_d, y_s);

    for (int it = 0; it < 3; ++it) {
        update_planar_kernel<<<dim3((N_HITS + 63) / 64, 3), 256, 0, stream>>>(
            h, y_d, y_s, off, csr_e, b1, W2P, b2, WuP, b_upd);
        sp_fused_kernel<<<(N_SPS + 63) / 64, 256, 0, stream>>>(h, off, csr_s, WspP, b_sp, sp);
        update_y_kernel<<<dim3((N_HITS + 63) / 64, 3), 256, 0, stream>>>(
            h, sp, off, csr_h, WnP, b_nx, W1dP, W1sP, y_d, y_s,
            W_sem, b_sem, (float*)d_out, it == 2 ? 1 : 0);
    }
}